// Round 5
// baseline (133.116 us; speedup 1.0000x reference)
//
#include <hip/hip_runtime.h>
#include <hip/hip_bf16.h>
#include <stdint.h>

// B=4, T=1024, C=1024, H=16, D=64
// ws layout (bf16 elems): xb[4096*1024] | wqkvT[3072*1024] | woT[1024*1024]
//                       | q[4M] | k[4M] | vT[4M] | O[4M]

typedef float f32x4 __attribute__((ext_vector_type(4)));
typedef __bf16 bf16x8 __attribute__((ext_vector_type(8)));
typedef __bf16 bf16x4 __attribute__((ext_vector_type(4)));

#define GAS __attribute__((address_space(1)))
#define LAS __attribute__((address_space(3)))

// ---------------------------------------------------------------- cast x -> bf16
__global__ __launch_bounds__(256) void cast_bf16_kernel(
    const float* __restrict__ in, __bf16* __restrict__ out, int n4) {
  int i = blockIdx.x * 256 + threadIdx.x;
  if (i < n4) {
    float4 f = ((const float4*)in)[i];
    bf16x4 o;
    o[0] = (__bf16)f.x; o[1] = (__bf16)f.y; o[2] = (__bf16)f.z; o[3] = (__bf16)f.w;
    ((bf16x4*)out)[i] = o;
  }
}

// ------------------------------------------- transpose f32 [rows x cols] -> bf16 [cols x rows]
__global__ __launch_bounds__(256) void transpose_cast_kernel(
    const float* __restrict__ src, __bf16* __restrict__ dst,
    int src_ld, int dst_ld, long long src_mstride, long long dst_mstride) {
  __shared__ float tile[64][65];
  const float* s = src + (size_t)blockIdx.z * src_mstride;
  __bf16* d = dst + (size_t)blockIdx.z * dst_mstride;
  int r0 = blockIdx.x * 64, c0 = blockIdx.y * 64;
  int tx = threadIdx.x & 63, ty = threadIdx.x >> 6;
#pragma unroll
  for (int rr = ty; rr < 64; rr += 4)
    tile[rr][tx] = s[(size_t)(r0 + rr) * src_ld + (c0 + tx)];
  __syncthreads();
#pragma unroll
  for (int rr = ty; rr < 64; rr += 4)
    d[(size_t)(c0 + rr) * dst_ld + (r0 + tx)] = (__bf16)tile[tx][rr];
}

// ---------------------------------------------------------------- QKV GEMM (8-phase ring)
// A[4096,1024] @ wqkvT^T -> q/k/vT scatter.  BM=BN=256, 512 thr (8 waves 2Mx4N,
// each 128x64 out).  K split into 32 subtiles of BK=32; LDS = 4-slot ring x
// (A 16KB + B 16KB) = 128KB.  Phase s: {12 ds_read_b128(slot s&3), issue
// stage(s+3) into slot (s+3)&3, lgkmcnt(0), 32 MFMA, vmcnt(8) [stage(s+1)
// landed; s+2,s+3 in flight across barrier], s_barrier}.  Tail 8->4->0.
// LDS layout per slot: [128 lines][128B] where line L holds logical rows
// {2L,2L+1} (64B each); 16B chunk c8 = ((row&1)<<2)|kchunk, stored at
// c8 ^ (line&7)  (swizzle applied on global source AND ds_read -> 2-way free).
__global__ __launch_bounds__(512, 2) void qkv_gemm_kernel(
    const __bf16* __restrict__ A, const __bf16* __restrict__ BT,
    __bf16* __restrict__ qo, __bf16* __restrict__ ko, __bf16* __restrict__ vo) {
  constexpr int K = 1024;
  __shared__ __align__(16) __bf16 Ash[4][128 * 64];
  __shared__ __align__(16) __bf16 Bsh[4][128 * 64];
  const int tid = threadIdx.x;
  const int wid = tid >> 6, lane = tid & 63;
  const int fr = lane & 15, fq = lane >> 4;
  const int m0 = blockIdx.x * 256, n0 = blockIdx.y * 256;
  const int wr = wid >> 2, wc = wid & 3;

  // staging per-lane coords: one load = 8 lines (16 rows); lane l -> line
  // (l>>3), phys chunk (l&7); logical c8 = (l&7)^(l>>3)
  const int s_c8 = (lane & 7) ^ (lane >> 3);
  const int s_rofs = 2 * (lane >> 3) + (s_c8 >> 2);   // row within 16-row group
  const int s_kel = (s_c8 & 3) * 8;                   // k elem offset in subtile

  // read-side element offsets (per slot)
  const int pA = ((((fr & 1) << 2) | fq) ^ (fr >> 1)) << 3;
  const int rdAe = wr * 4096 + (fr >> 1) * 64 + pA;
  const int rdBe = wc * 2048 + (fr >> 1) * 64 + pA;

  f32x4 acc[8][4] = {};

  auto stage = [&](int s) {
    const int slot = s & 3;
    const int k0 = s * 32;
#pragma unroll
    for (int i = 0; i < 2; ++i) {
      int j = 2 * wid + i;                            // 0..15, wave-uniform
      int r = j * 16 + s_rofs;                        // logical row 0..255
      const __bf16* gA = A + (size_t)(m0 + r) * K + k0 + s_kel;
      __builtin_amdgcn_global_load_lds((const GAS void*)gA,
          (LAS void*)&Ash[slot][j * 512], 16, 0, 0);
    }
#pragma unroll
    for (int i = 0; i < 2; ++i) {
      int j = 2 * wid + i;
      int r = j * 16 + s_rofs;
      const __bf16* gB = BT + (size_t)(n0 + r) * K + k0 + s_kel;
      __builtin_amdgcn_global_load_lds((const GAS void*)gB,
          (LAS void*)&Bsh[slot][j * 512], 16, 0, 0);
    }
  };

  auto phase = [&](int s, bool do_stage, int vm) {
    const int slot = s & 3;
    const __bf16* Ab = Ash[slot];
    const __bf16* Bb = Bsh[slot];
    bf16x8 af[8], bfv[4];
#pragma unroll
    for (int mi = 0; mi < 8; ++mi)
      af[mi] = *(const bf16x8*)&Ab[rdAe + mi * 512];
#pragma unroll
    for (int ni = 0; ni < 4; ++ni)
      bfv[ni] = *(const bf16x8*)&Bb[rdBe + ni * 512];
    if (do_stage) stage(s + 3);
    asm volatile("s_waitcnt lgkmcnt(0)" ::: "memory");
    __builtin_amdgcn_sched_barrier(0);
    __builtin_amdgcn_s_setprio(1);
#pragma unroll
    for (int mi = 0; mi < 8; ++mi)
#pragma unroll
      for (int ni = 0; ni < 4; ++ni)
        acc[mi][ni] = __builtin_amdgcn_mfma_f32_16x16x32_bf16(af[mi], bfv[ni], acc[mi][ni], 0, 0, 0);
    __builtin_amdgcn_s_setprio(0);
    __builtin_amdgcn_sched_barrier(0);
    if (vm == 8)      asm volatile("s_waitcnt vmcnt(8)" ::: "memory");
    else if (vm == 4) asm volatile("s_waitcnt vmcnt(4)" ::: "memory");
    else if (vm == 0) asm volatile("s_waitcnt vmcnt(0)" ::: "memory");
    if (vm >= 0) {
      __builtin_amdgcn_s_barrier();
      __builtin_amdgcn_sched_barrier(0);
    }
  };

  // prologue: 3 subtiles in flight, confirm subtile 0
  stage(0); stage(1); stage(2);
  asm volatile("s_waitcnt vmcnt(8)" ::: "memory");
  __builtin_amdgcn_s_barrier();
  __builtin_amdgcn_sched_barrier(0);

  for (int s = 0; s < 29; ++s) phase(s, true, 8);   // steady state: vmcnt(8)
  phase(29, false, 4);
  phase(30, false, 0);
  phase(31, false, -1);                             // last: no wait, no barrier

  // epilogue: scatter q (pre-scaled 1/8), k as [B,H,T,D]; v transposed [B,H,D,T]
#pragma unroll
  for (int mi = 0; mi < 8; ++mi) {
#pragma unroll
    for (int ni = 0; ni < 4; ++ni) {
      int n = n0 + wc * 64 + ni * 16 + fr;
      int mb = m0 + wr * 128 + mi * 16 + fq * 4;
      int sec = n >> 10, nl = n & 1023;
      int h = nl >> 6, dd = nl & 63;
#pragma unroll
      for (int r = 0; r < 4; ++r) {
        int m = mb + r;
        int b = m >> 10, tt = m & 1023;
        float val = acc[mi][ni][r];
        if (sec == 0) {
          qo[(((size_t)b * 16 + h) * 1024 + tt) * 64 + dd] = (__bf16)(val * 0.125f);
        } else if (sec == 1) {
          ko[(((size_t)b * 16 + h) * 1024 + tt) * 64 + dd] = (__bf16)val;
        } else {
          vo[(((size_t)b * 16 + h) * 64 + dd) * 1024 + tt] = (__bf16)val;
        }
      }
    }
  }
}

// ---------------------------------------------------------------- out-proj GEMM (2ph 128x128)
// C = A @ BT^T + bias, fp32 out.  grid (32,8) = 256 blocks.
__global__ __launch_bounds__(256) void gemm_out_kernel(
    const __bf16* __restrict__ A, const __bf16* __restrict__ BT, int N,
    float* __restrict__ Cout, const float* __restrict__ bias) {
  constexpr int K = 1024;
  __shared__ __align__(16) __bf16 Ash[2][128 * 32];
  __shared__ __align__(16) __bf16 Bsh[2][128 * 32];
  const int tid = threadIdx.x;
  const int wid = tid >> 6, lane = tid & 63;
  const int fr = lane & 15, fq = lane >> 4;
  const int m0 = blockIdx.x * 128, n0 = blockIdx.y * 128;
  const int wr = wid >> 1, wc = wid & 1;
  const int srow = lane >> 2;
  const int scol = (((lane & 3) ^ ((lane >> 3) & 3))) * 8;
  const int swz = ((fq ^ ((fr >> 1) & 3))) << 3;

  f32x4 acc[4][4] = {};

  auto stage = [&](int k0, int buf) {
#pragma unroll
    for (int i = 0; i < 2; ++i) {
      int chunk = wid * 2 + i;
      int row = chunk * 16 + srow;
      const __bf16* gA = A + (size_t)(m0 + row) * K + k0 + scol;
      const __bf16* gB = BT + (size_t)(n0 + row) * K + k0 + scol;
      __builtin_amdgcn_global_load_lds((const GAS void*)gA, (LAS void*)&Ash[buf][chunk * 512], 16, 0, 0);
      __builtin_amdgcn_global_load_lds((const GAS void*)gB, (LAS void*)&Bsh[buf][chunk * 512], 16, 0, 0);
    }
  };

  stage(0, 0);
  __syncthreads();
  int buf = 0;
  for (int k0 = 0; k0 < K; k0 += 32) {
    if (k0 + 32 < K) stage(k0 + 32, buf ^ 1);
    bf16x8 af[4], bfr[4];
#pragma unroll
    for (int mi = 0; mi < 4; ++mi) {
      int r = wr * 64 + mi * 16 + fr;
      af[mi] = *(const bf16x8*)&Ash[buf][r * 32 + swz];
    }
#pragma unroll
    for (int ni = 0; ni < 4; ++ni) {
      int r = wc * 64 + ni * 16 + fr;
      bfr[ni] = *(const bf16x8*)&Bsh[buf][r * 32 + swz];
    }
    __builtin_amdgcn_s_setprio(1);
#pragma unroll
    for (int mi = 0; mi < 4; ++mi)
#pragma unroll
      for (int ni = 0; ni < 4; ++ni)
        acc[mi][ni] = __builtin_amdgcn_mfma_f32_16x16x32_bf16(af[mi], bfr[ni], acc[mi][ni], 0, 0, 0);
    __builtin_amdgcn_s_setprio(0);
    __syncthreads();
    buf ^= 1;
  }

#pragma unroll
  for (int mi = 0; mi < 4; ++mi) {
#pragma unroll
    for (int ni = 0; ni < 4; ++ni) {
      int n = n0 + wc * 64 + ni * 16 + fr;
      int mb = m0 + wr * 64 + mi * 16 + fq * 4;
#pragma unroll
      for (int r = 0; r < 4; ++r) {
        int m = mb + r;
        Cout[(size_t)m * N + n] = acc[mi][ni][r] + bias[n];
      }
    }
  }
}

// ---------------------------------------------------------------- flash attention (causal)
// grid (8, B*H); 256 threads = 4 waves. Block bx handles q-tiles {bx, 15-bx},
// sharing each staged K/V tile (balanced: 17 compute-units per block).
__global__ __launch_bounds__(256) void attn_fwd_kernel(
    const __bf16* __restrict__ Q, const __bf16* __restrict__ Kg,
    const __bf16* __restrict__ Vt, __bf16* __restrict__ O) {
  __shared__ __align__(16) __bf16 Ksh[2][64 * 64];
  __shared__ __align__(16) __bf16 VTs[2][64 * 64];
  __shared__ __align__(16) __bf16 Psh[4][16 * 72];

  const int bx = blockIdx.x, bh = blockIdx.y;
  const int b = bh >> 4, h = bh & 15;
  const size_t base = (size_t)bh * 1024 * 64;
  const int tid = threadIdx.x, wid = tid >> 6, lane = tid & 63;
  const int fr = lane & 15, fq = lane >> 4;
  const int qta = bx, qtb = 15 - bx;
  const int q0a = qta * 64, q0b = qtb * 64;

  bf16x8 qa[2], qbf[2];
  {
    int qra = q0a + wid * 16 + fr;
    qa[0] = *(const bf16x8*)&Q[base + (size_t)qra * 64 + fq * 8];
    qa[1] = *(const bf16x8*)&Q[base + (size_t)qra * 64 + 32 + fq * 8];
    int qrb = q0b + wid * 16 + fr;
    qbf[0] = *(const bf16x8*)&Q[base + (size_t)qrb * 64 + fq * 8];
    qbf[1] = *(const bf16x8*)&Q[base + (size_t)qrb * 64 + 32 + fq * 8];
  }
  f32x4 oa[4] = {}, ob[4] = {};
  float ma = -1e30f, la = 0.f, mb = -1e30f, lb = 0.f;

  const int lrow8 = lane >> 3;
  const int schunk = (lane & 7) ^ lrow8;

  auto stage = [&](int st, int buf) {
    const int s0 = st * 64;
#pragma unroll
    for (int i = 0; i < 2; ++i) {
      int rowbase = i * 32 + wid * 8;
      int row = rowbase + lrow8;
      const __bf16* gK = Kg + base + (size_t)(s0 + row) * 64 + schunk * 8;
      __builtin_amdgcn_global_load_lds((const GAS void*)gK,
          (LAS void*)&Ksh[buf][rowbase * 64], 16, 0, 0);
      const __bf16* gV = Vt + base + (size_t)row * 1024 + s0 + schunk * 8;
      __builtin_amdgcn_global_load_lds((const GAS void*)gV,
          (LAS void*)&VTs[buf][rowbase * 64], 16, 0, 0);
    }
  };

  auto compute = [&](int buf, int s0, const bf16x8* qf, f32x4* oacc,
                     float& m, float& l, int q0x, bool maskT) {
    f32x4 s[4];
    __builtin_amdgcn_s_setprio(1);
#pragma unroll
    for (int sf = 0; sf < 4; ++sf) {
      int row = sf * 16 + fr, rx = fr & 7;
      bf16x8 kf0 = *(const bf16x8*)&Ksh[buf][row * 64 + ((fq ^ rx) << 3)];
      f32x4 z = {};
      s[sf] = __builtin_amdgcn_mfma_f32_16x16x32_bf16(kf0, qf[0], z, 0, 0, 0);
      bf16x8 kf1 = *(const bf16x8*)&Ksh[buf][row * 64 + (((4 + fq) ^ rx) << 3)];
      s[sf] = __builtin_amdgcn_mfma_f32_16x16x32_bf16(kf1, qf[1], s[sf], 0, 0, 0);
    }
    __builtin_amdgcn_s_setprio(0);

    const int qg = q0x + wid * 16 + fr;
    float sv[4][4];
    float mx = -1e30f;
#pragma unroll
    for (int sf = 0; sf < 4; ++sf)
#pragma unroll
      for (int r = 0; r < 4; ++r) {
        float x = s[sf][r];
        if (maskT) { int sg = s0 + sf * 16 + fq * 4 + r; if (sg > qg) x = -1e30f; }
        sv[sf][r] = x;
        mx = fmaxf(mx, x);
      }
    mx = fmaxf(mx, __shfl_xor(mx, 16));
    mx = fmaxf(mx, __shfl_xor(mx, 32));
    float mnew = fmaxf(m, mx);
    float alpha = __expf(m - mnew);
    m = mnew;
    float rs = 0.f;
#pragma unroll
    for (int sf = 0; sf < 4; ++sf) {
      bf16x4 pk;
#pragma unroll
      for (int r = 0; r < 4; ++r) {
        float p = __expf(sv[sf][r] - mnew);
        rs += p;
        pk[r] = (__bf16)p;
      }
      *(bf16x4*)&Psh[wid][fr * 72 + sf * 16 + fq * 4] = pk;
    }
    rs += __shfl_xor(rs, 16);
    rs += __shfl_xor(rs, 32);
    l = l * alpha + rs;
    float ar[4];
#pragma unroll
    for (int r = 0; r < 4; ++r) ar[r] = __shfl(alpha, (lane & 48) | (fq * 4 + r));
#pragma unroll
    for (int df = 0; df < 4; ++df)
#pragma unroll
      for (int r = 0; r < 4; ++r) oacc[df][r] *= ar[r];

    __builtin_amdgcn_s_setprio(1);
#pragma unroll
    for (int kk = 0; kk < 2; ++kk) {
      bf16x8 pf = *(const bf16x8*)&Psh[wid][fr * 72 + kk * 32 + fq * 8];
#pragma unroll
      for (int df = 0; df < 4; ++df) {
        int row = df * 16 + fr;
        bf16x8 vf = *(const bf16x8*)&VTs[buf][row * 64 + ((((kk << 2) | fq) ^ (fr & 7)) << 3)];
        oacc[df] = __builtin_amdgcn_mfma_f32_16x16x32_bf16(pf, vf, oacc[df], 0, 0, 0);
      }
    }
    __builtin_amdgcn_s_setprio(0);
  };

  stage(0, 0);
  __syncthreads();
  int cur = 0;
  for (int st = 0; st <= qtb; ++st) {
    if (st < qtb) stage(st + 1, cur ^ 1);
    compute(cur, st * 64, qbf, ob, mb, lb, q0b, st == qtb);
    if (st <= qta) compute(cur, st * 64, qa, oa, ma, la, q0a, st == qta);
    __syncthreads();
    cur ^= 1;
  }

  auto epilogue = [&](const f32x4* oacc, float l, int q0x) {
    float lr[4];
#pragma unroll
    for (int r = 0; r < 4; ++r) lr[r] = __shfl(l, (lane & 48) | (fq * 4 + r));
#pragma unroll
    for (int r = 0; r < 4; ++r) {
      float inv = 1.0f / lr[r];
      int t = q0x + wid * 16 + fq * 4 + r;
      size_t orow = ((size_t)b * 1024 + t) * 1024 + h * 64;
#pragma unroll
      for (int df = 0; df < 4; ++df)
        O[orow + df * 16 + fr] = (__bf16)(oacc[df][r] * inv);
    }
  };
  epilogue(ob, lb, q0b);
  epilogue(oa, la, q0a);
}

// ---------------------------------------------------------------- launch
extern "C" void kernel_launch(void* const* d_in, const int* in_sizes, int n_in,
                              void* d_out, int out_size, void* d_ws, size_t ws_size,
                              hipStream_t stream) {
  const float* x  = (const float*)d_in[0];
  const float* Wq = (const float*)d_in[1];
  const float* Wk = (const float*)d_in[2];
  const float* Wv = (const float*)d_in[3];
  const float* Wo = (const float*)d_in[4];
  const float* bo = (const float*)d_in[5];
  float* out = (float*)d_out;

  __bf16* xb    = (__bf16*)d_ws;                    // 4096x1024
  __bf16* wqkvT = xb + (size_t)4096 * 1024;         // 3072x1024
  __bf16* woT   = wqkvT + (size_t)3072 * 1024;      // 1024x1024
  __bf16* qb    = woT + (size_t)1024 * 1024;        // [B,H,T,D]
  __bf16* kb    = qb + (size_t)4 * 16 * 1024 * 64;  // [B,H,T,D]
  __bf16* vtb   = kb + (size_t)4 * 16 * 1024 * 64;  // [B,H,D,T]
  __bf16* Ob    = vtb + (size_t)4 * 16 * 1024 * 64; // [B*T, H*D]

  cast_bf16_kernel<<<4096, 256, 0, stream>>>(x, xb, 4194304 / 4);
  transpose_cast_kernel<<<dim3(16, 1, 16), 256, 0, stream>>>(Wq, wqkvT, 64, 1024, 65536, 65536);
  transpose_cast_kernel<<<dim3(16, 1, 16), 256, 0, stream>>>(Wk, wqkvT + (size_t)1024 * 1024, 64, 1024, 65536, 65536);
  transpose_cast_kernel<<<dim3(16, 1, 16), 256, 0, stream>>>(Wv, wqkvT + (size_t)2048 * 1024, 64, 1024, 65536, 65536);
  transpose_cast_kernel<<<dim3(16, 16, 1), 256, 0, stream>>>(Wo, woT, 1024, 1024, 0, 0);

  // QKV projection: [4096,1024] @ [1024,3072], 8-phase ring pipeline
  qkv_gemm_kernel<<<dim3(16, 12), 512, 0, stream>>>(xb, wqkvT, qb, kb, vtb);

  // causal flash attention (balanced paired q-tiles)
  attn_fwd_kernel<<<dim3(8, 64), 256, 0, stream>>>(qb, kb, vtb, Ob);

  // output projection + bias: [4096,1024] @ [1024,1024]
  gemm_out_kernel<<<dim3(32, 8), 256, 0, stream>>>(Ob, woT, 1024, out, bo);
}

// Round 6
// 102.313 us; speedup vs baseline: 1.3011x; 1.3011x over previous
//
#include <hip/hip_runtime.h>
#include <hip/hip_bf16.h>
#include <stdint.h>

// B=4, T=1024, C=1024, H=16, D=64
// ws layout (bf16 elems): xb[4096*1024] | wqkvT[3072*1024] | woT[1024*1024]
//                       | q[4M] | k[4M] | vT[4M] | O[4M]

typedef float f32x4 __attribute__((ext_vector_type(4)));
typedef __bf16 bf16x8 __attribute__((ext_vector_type(8)));
typedef __bf16 bf16x4 __attribute__((ext_vector_type(4)));

#define GAS __attribute__((address_space(1)))
#define LAS __attribute__((address_space(3)))

// ---------------------------------------------------------------- cast x -> bf16
__global__ __launch_bounds__(256) void cast_bf16_kernel(
    const float* __restrict__ in, __bf16* __restrict__ out, int n4) {
  int i = blockIdx.x * 256 + threadIdx.x;
  if (i < n4) {
    float4 f = ((const float4*)in)[i];
    bf16x4 o;
    o[0] = (__bf16)f.x; o[1] = (__bf16)f.y; o[2] = (__bf16)f.z; o[3] = (__bf16)f.w;
    ((bf16x4*)out)[i] = o;
  }
}

// ------------------------------------------- Wq/Wk/Wv merged transpose:
// [H][C][D] fp32 -> wqkvT rows n = sec*1024 + h*64 + d, cols C (bf16)
__global__ __launch_bounds__(256) void transpose_qkv_kernel(
    const float* __restrict__ Wq, const float* __restrict__ Wk,
    const float* __restrict__ Wv, __bf16* __restrict__ dst_base) {
  __shared__ float tile[64][65];
  int z = blockIdx.z;                                  // 0..47
  const float* s = (z < 16 ? Wq : (z < 32 ? Wk : Wv)) + (size_t)(z & 15) * 65536;
  __bf16* d = dst_base + (size_t)z * 65536;            // 64 rows x 1024
  int r0 = blockIdx.x * 64;                            // C-tile
  int tx = threadIdx.x & 63, ty = threadIdx.x >> 6;
#pragma unroll
  for (int rr = ty; rr < 64; rr += 4)
    tile[rr][tx] = s[(size_t)(r0 + rr) * 64 + tx];
  __syncthreads();
#pragma unroll
  for (int rr = ty; rr < 64; rr += 4)
    d[(size_t)rr * 1024 + (r0 + tx)] = (__bf16)tile[tx][rr];
}

// ------------------------------------------- transpose f32 [rows x cols] -> bf16 [cols x rows]
__global__ __launch_bounds__(256) void transpose_cast_kernel(
    const float* __restrict__ src, __bf16* __restrict__ dst,
    int src_ld, int dst_ld) {
  __shared__ float tile[64][65];
  int r0 = blockIdx.x * 64, c0 = blockIdx.y * 64;
  int tx = threadIdx.x & 63, ty = threadIdx.x >> 6;
#pragma unroll
  for (int rr = ty; rr < 64; rr += 4)
    tile[rr][tx] = src[(size_t)(r0 + rr) * src_ld + (c0 + tx)];
  __syncthreads();
#pragma unroll
  for (int rr = ty; rr < 64; rr += 4)
    dst[(size_t)(c0 + rr) * dst_ld + (r0 + tx)] = (__bf16)tile[tx][rr];
}

// ---------------------------------------------------------------- GEMM (A row-major, BT = B^T row-major)
// 128x128 tile, BK=32, 256 threads (4 waves 2x2, each 64x64).  Round-3 proven
// 2-phase dbuf structure (2-3 blocks/CU inter-block overlap is the latency
// hiding; deep in-block pipelines at 1 blk/CU measured WORSE, r4/r5).
// XOR-swizzled LDS (chunk ^= (row>>1)&3, both sides) -> 0 bank conflicts (r3).
// MODE 0: q (pre-scaled 1/8), k scatter [B,H,T,D]; V-blocks (sec==2) restage
//         the tile through LDS (aliased, 272B-padded rows) for fully-coalesced
//         16B vT writes instead of 2B/2KB-stride scatter.
// MODE 1: fp32 out + bias
template <int MODE>
__global__ __launch_bounds__(256) void gemm_bt_kernel(
    const __bf16* __restrict__ A, const __bf16* __restrict__ BT, int N,
    __bf16* __restrict__ qo, __bf16* __restrict__ ko, __bf16* __restrict__ vo,
    float* __restrict__ Cout, const float* __restrict__ bias) {
  constexpr int K = 1024;
  extern __shared__ __align__(16) char smem_raw[];
  __bf16* Ash = (__bf16*)smem_raw;                 // [2][128*32]
  __bf16* Bsh = Ash + 2 * 128 * 32;                // [2][128*32]
  const int tid = threadIdx.x;
  const int wid = tid >> 6, lane = tid & 63;
  const int fr = lane & 15, fq = lane >> 4;
  const int m0 = blockIdx.x * 128, n0 = blockIdx.y * 128;
  const int wr = wid >> 1, wc = wid & 1;
  const int srow = lane >> 2;
  const int scol = (((lane & 3) ^ ((lane >> 3) & 3))) * 8;   // pre-swizzled src chunk
  const int swz = ((fq ^ ((fr >> 1) & 3))) << 3;             // read-side swizzle

  f32x4 acc[4][4] = {};

  auto stage = [&](int k0, int buf) {
#pragma unroll
    for (int i = 0; i < 2; ++i) {
      int chunk = wid * 2 + i;
      int row = chunk * 16 + srow;
      const __bf16* gA = A + (size_t)(m0 + row) * K + k0 + scol;
      const __bf16* gB = BT + (size_t)(n0 + row) * K + k0 + scol;
      __builtin_amdgcn_global_load_lds((const GAS void*)gA, (LAS void*)&Ash[buf * 4096 + chunk * 512], 16, 0, 0);
      __builtin_amdgcn_global_load_lds((const GAS void*)gB, (LAS void*)&Bsh[buf * 4096 + chunk * 512], 16, 0, 0);
    }
  };

  stage(0, 0);
  __syncthreads();
  int buf = 0;
  for (int k0 = 0; k0 < K; k0 += 32) {
    if (k0 + 32 < K) stage(k0 + 32, buf ^ 1);
    bf16x8 af[4], bfr[4];
#pragma unroll
    for (int mi = 0; mi < 4; ++mi) {
      int r = wr * 64 + mi * 16 + fr;
      af[mi] = *(const bf16x8*)&Ash[buf * 4096 + r * 32 + swz];
    }
#pragma unroll
    for (int ni = 0; ni < 4; ++ni) {
      int r = wc * 64 + ni * 16 + fr;
      bfr[ni] = *(const bf16x8*)&Bsh[buf * 4096 + r * 32 + swz];
    }
    __builtin_amdgcn_s_setprio(1);
#pragma unroll
    for (int mi = 0; mi < 4; ++mi)
#pragma unroll
      for (int ni = 0; ni < 4; ++ni)
        acc[mi][ni] = __builtin_amdgcn_mfma_f32_16x16x32_bf16(af[mi], bfr[ni], acc[mi][ni], 0, 0, 0);
    __builtin_amdgcn_s_setprio(0);
    __syncthreads();
    buf ^= 1;
  }

  if (MODE == 0 && (n0 >> 10) == 2) {
    // ---- V-block: LDS restage for coalesced transposed writes ----
    // spill [n_local 0..127][m_local 0..127], rows padded to 136 elems (272B).
    __bf16* spill = (__bf16*)smem_raw;   // aliases Ash/Bsh; safe after final sync
#pragma unroll
    for (int mi = 0; mi < 4; ++mi)
#pragma unroll
      for (int ni = 0; ni < 4; ++ni) {
        int nl = wc * 64 + ni * 16 + fr;
        int ml = wr * 64 + mi * 16 + fq * 4;   // r packed (t-consecutive)
        bf16x4 pk;
#pragma unroll
        for (int r = 0; r < 4; ++r) pk[r] = (__bf16)acc[mi][ni][r];
        *(bf16x4*)&spill[nl * 136 + ml] = pk;
      }
    __syncthreads();
    const int b = m0 >> 10, t0 = m0 & 1023;
    const int lrow = lane >> 4, lch = lane & 15;
#pragma unroll
    for (int i = 0; i < 8; ++i) {
      int nl = wid * 32 + i * 4 + lrow;
      bf16x8 v = *(const bf16x8*)&spill[nl * 136 + lch * 8];
      int nn = (n0 & 1023) + nl;               // h*64+dd
      *(bf16x8*)&vo[(((size_t)b * 16 + (nn >> 6)) * 64 + (nn & 63)) * 1024 + t0 + lch * 8] = v;
    }
    return;
  }

#pragma unroll
  for (int mi = 0; mi < 4; ++mi) {
#pragma unroll
    for (int ni = 0; ni < 4; ++ni) {
      int n = n0 + wc * 64 + ni * 16 + fr;
      int mb = m0 + wr * 64 + mi * 16 + fq * 4;
#pragma unroll
      for (int r = 0; r < 4; ++r) {
        int m = mb + r;
        float val = acc[mi][ni][r];
        if (MODE == 0) {
          int sec = n >> 10, nl = n & 1023;
          int h = nl >> 6, dd = nl & 63;
          int b = m >> 10, t = m & 1023;
          if (sec == 0) {
            qo[(((size_t)b * 16 + h) * 1024 + t) * 64 + dd] = (__bf16)(val * 0.125f);
          } else {
            ko[(((size_t)b * 16 + h) * 1024 + t) * 64 + dd] = (__bf16)val;
          }
        } else {
          Cout[(size_t)m * N + n] = val + bias[n];
        }
      }
    }
  }
}

// ---------------------------------------------------------------- flash attention (causal)
// 512 blocks, 256 threads = 4 waves.  Block handles q-tiles {bx, 15-bx} of one
// (b,h), sharing each staged K/V tile (balanced: 17 compute-units per block).
// Block remap: bid % 8 == bh % 8, so the 8 blocks of one bh land on ONE XCD
// (K/V re-reads hit that XCD's L2; 8 bh per XCD = 1MB < 4MB L2).
__global__ __launch_bounds__(256) void attn_fwd_kernel(
    const __bf16* __restrict__ Q, const __bf16* __restrict__ Kg,
    const __bf16* __restrict__ Vt, __bf16* __restrict__ O) {
  __shared__ __align__(16) __bf16 Ksh[2][64 * 64];
  __shared__ __align__(16) __bf16 VTs[2][64 * 64];
  __shared__ __align__(16) __bf16 Psh[4][16 * 72];

  const int bid = blockIdx.x;
  const int bx = (bid >> 3) & 7;
  const int bh = (bid & 7) | ((bid >> 6) << 3);
  const int b = bh >> 4, h = bh & 15;
  const size_t base = (size_t)bh * 1024 * 64;
  const int tid = threadIdx.x, wid = tid >> 6, lane = tid & 63;
  const int fr = lane & 15, fq = lane >> 4;
  const int qta = bx, qtb = 15 - bx;
  const int q0a = qta * 64, q0b = qtb * 64;

  bf16x8 qa[2], qbf[2];
  {
    int qra = q0a + wid * 16 + fr;
    qa[0] = *(const bf16x8*)&Q[base + (size_t)qra * 64 + fq * 8];
    qa[1] = *(const bf16x8*)&Q[base + (size_t)qra * 64 + 32 + fq * 8];
    int qrb = q0b + wid * 16 + fr;
    qbf[0] = *(const bf16x8*)&Q[base + (size_t)qrb * 64 + fq * 8];
    qbf[1] = *(const bf16x8*)&Q[base + (size_t)qrb * 64 + 32 + fq * 8];
  }
  f32x4 oa[4] = {}, ob[4] = {};
  float ma = -1e30f, la = 0.f, mb = -1e30f, lb = 0.f;

  const int lrow8 = lane >> 3;
  const int schunk = (lane & 7) ^ lrow8;

  auto stage = [&](int st, int buf) {
    const int s0 = st * 64;
#pragma unroll
    for (int i = 0; i < 2; ++i) {
      int rowbase = i * 32 + wid * 8;
      int row = rowbase + lrow8;
      const __bf16* gK = Kg + base + (size_t)(s0 + row) * 64 + schunk * 8;
      __builtin_amdgcn_global_load_lds((const GAS void*)gK,
          (LAS void*)&Ksh[buf][rowbase * 64], 16, 0, 0);
      const __bf16* gV = Vt + base + (size_t)row * 1024 + s0 + schunk * 8;
      __builtin_amdgcn_global_load_lds((const GAS void*)gV,
          (LAS void*)&VTs[buf][rowbase * 64], 16, 0, 0);
    }
  };

  auto compute = [&](int buf, int s0, const bf16x8* qf, f32x4* oacc,
                     float& m, float& l, int q0x, bool maskT) {
    f32x4 s[4];
    __builtin_amdgcn_s_setprio(1);
#pragma unroll
    for (int sf = 0; sf < 4; ++sf) {
      int row = sf * 16 + fr, rx = fr & 7;
      bf16x8 kf0 = *(const bf16x8*)&Ksh[buf][row * 64 + ((fq ^ rx) << 3)];
      f32x4 z = {};
      s[sf] = __builtin_amdgcn_mfma_f32_16x16x32_bf16(kf0, qf[0], z, 0, 0, 0);
      bf16x8 kf1 = *(const bf16x8*)&Ksh[buf][row * 64 + (((4 + fq) ^ rx) << 3)];
      s[sf] = __builtin_amdgcn_mfma_f32_16x16x32_bf16(kf1, qf[1], s[sf], 0, 0, 0);
    }
    __builtin_amdgcn_s_setprio(0);

    const int qg = q0x + wid * 16 + fr;
    float sv[4][4];
    float mx = -1e30f;
#pragma unroll
    for (int sf = 0; sf < 4; ++sf)
#pragma unroll
      for (int r = 0; r < 4; ++r) {
        float x = s[sf][r];
        if (maskT) { int sg = s0 + sf * 16 + fq * 4 + r; if (sg > qg) x = -1e30f; }
        sv[sf][r] = x;
        mx = fmaxf(mx, x);
      }
    mx = fmaxf(mx, __shfl_xor(mx, 16));
    mx = fmaxf(mx, __shfl_xor(mx, 32));
    float mnew = fmaxf(m, mx);
    float alpha = __expf(m - mnew);
    m = mnew;
    float rs = 0.f;
#pragma unroll
    for (int sf = 0; sf < 4; ++sf) {
      bf16x4 pk;
#pragma unroll
      for (int r = 0; r < 4; ++r) {
        float p = __expf(sv[sf][r] - mnew);
        rs += p;
        pk[r] = (__bf16)p;
      }
      *(bf16x4*)&Psh[wid][fr * 72 + sf * 16 + fq * 4] = pk;
    }
    rs += __shfl_xor(rs, 16);
    rs += __shfl_xor(rs, 32);
    l = l * alpha + rs;
    float ar[4];
#pragma unroll
    for (int r = 0; r < 4; ++r) ar[r] = __shfl(alpha, (lane & 48) | (fq * 4 + r));
#pragma unroll
    for (int df = 0; df < 4; ++df)
#pragma unroll
      for (int r = 0; r < 4; ++r) oacc[df][r] *= ar[r];

    __builtin_amdgcn_s_setprio(1);
#pragma unroll
    for (int kk = 0; kk < 2; ++kk) {
      bf16x8 pf = *(const bf16x8*)&Psh[wid][fr * 72 + kk * 32 + fq * 8];
#pragma unroll
      for (int df = 0; df < 4; ++df) {
        int row = df * 16 + fr;
        bf16x8 vf = *(const bf16x8*)&VTs[buf][row * 64 + ((((kk << 2) | fq) ^ (fr & 7)) << 3)];
        oacc[df] = __builtin_amdgcn_mfma_f32_16x16x32_bf16(pf, vf, oacc[df], 0, 0, 0);
      }
    }
    __builtin_amdgcn_s_setprio(0);
  };

  stage(0, 0);
  __syncthreads();
  int cur = 0;
  for (int st = 0; st <= qtb; ++st) {
    if (st < qtb) stage(st + 1, cur ^ 1);
    compute(cur, st * 64, qbf, ob, mb, lb, q0b, st == qtb);
    if (st <= qta) compute(cur, st * 64, qa, oa, ma, la, q0a, st == qta);
    __syncthreads();
    cur ^= 1;
  }

  auto epilogue = [&](const f32x4* oacc, float l, int q0x) {
    float lr[4];
#pragma unroll
    for (int r = 0; r < 4; ++r) lr[r] = __shfl(l, (lane & 48) | (fq * 4 + r));
#pragma unroll
    for (int r = 0; r < 4; ++r) {
      float inv = 1.0f / lr[r];
      int t = q0x + wid * 16 + fq * 4 + r;
      size_t orow = ((size_t)b * 1024 + t) * 1024 + h * 64;
#pragma unroll
      for (int df = 0; df < 4; ++df)
        O[orow + df * 16 + fr] = (__bf16)(oacc[df][r] * inv);
    }
  };
  epilogue(ob, lb, q0b);
  epilogue(oa, la, q0a);
}

// ---------------------------------------------------------------- launch
extern "C" void kernel_launch(void* const* d_in, const int* in_sizes, int n_in,
                              void* d_out, int out_size, void* d_ws, size_t ws_size,
                              hipStream_t stream) {
  const float* x  = (const float*)d_in[0];
  const float* Wq = (const float*)d_in[1];
  const float* Wk = (const float*)d_in[2];
  const float* Wv = (const float*)d_in[3];
  const float* Wo = (const float*)d_in[4];
  const float* bo = (const float*)d_in[5];
  float* out = (float*)d_out;

  __bf16* xb    = (__bf16*)d_ws;                    // 4096x1024
  __bf16* wqkvT = xb + (size_t)4096 * 1024;         // 3072x1024
  __bf16* woT   = wqkvT + (size_t)3072 * 1024;      // 1024x1024
  __bf16* qb    = woT + (size_t)1024 * 1024;        // [B,H,T,D]
  __bf16* kb    = qb + (size_t)4 * 16 * 1024 * 64;  // [B,H,T,D]
  __bf16* vtb   = kb + (size_t)4 * 16 * 1024 * 64;  // [B,H,D,T]
  __bf16* Ob    = vtb + (size_t)4 * 16 * 1024 * 64; // [B*T, H*D]

  cast_bf16_kernel<<<4096, 256, 0, stream>>>(x, xb, 4194304 / 4);
  transpose_qkv_kernel<<<dim3(16, 1, 48), 256, 0, stream>>>(Wq, Wk, Wv, wqkvT);
  transpose_cast_kernel<<<dim3(16, 16), 256, 0, stream>>>(Wo, woT, 1024, 1024);

  // QKV projection: [4096,1024] @ [1024,3072]   (dyn LDS: 32KB dbuf, 34KB V-restage)
  gemm_bt_kernel<0><<<dim3(32, 24), 256, 34816, stream>>>(xb, wqkvT, 3072, qb, kb, vtb, nullptr, nullptr);

  // causal flash attention (balanced paired q-tiles, XCD-grouped by bh)
  attn_fwd_kernel<<<512, 256, 0, stream>>>(qb, kb, vtb, Ob);

  // output projection + bias: [4096,1024] @ [1024,1024]
  gemm_bt_kernel<1><<<dim3(32, 8), 256, 32768, stream>>>(Ob, woT, 1024, nullptr, nullptr, nullptr, out, bo);
}

// Round 8
// 95.273 us; speedup vs baseline: 1.3972x; 1.0739x over previous
//
#include <hip/hip_runtime.h>
#include <hip/hip_bf16.h>
#include <stdint.h>

// B=4, T=1024, C=1024, H=16, D=64
// ws layout (bf16 elems): xb[4096*1024] | wqkvT[3072*1024] | woT[1024*1024]
//                       | q[4M] | k[4M] | vT[4M] | O[4M]

typedef float f32x4 __attribute__((ext_vector_type(4)));
typedef __bf16 bf16x8 __attribute__((ext_vector_type(8)));
typedef __bf16 bf16x4 __attribute__((ext_vector_type(4)));

#define GAS __attribute__((address_space(1)))
#define LAS __attribute__((address_space(3)))

// ---------------------------------------------------------------- cast x -> bf16
__global__ __launch_bounds__(256) void cast_bf16_kernel(
    const float* __restrict__ in, __bf16* __restrict__ out, int n4) {
  int i = blockIdx.x * 256 + threadIdx.x;
  if (i < n4) {
    float4 f = ((const float4*)in)[i];
    bf16x4 o;
    o[0] = (__bf16)f.x; o[1] = (__bf16)f.y; o[2] = (__bf16)f.z; o[3] = (__bf16)f.w;
    ((bf16x4*)out)[i] = o;
  }
}

// ------------------------------------------- Wq/Wk/Wv merged transpose:
// [H][C][D] fp32 -> wqkvT rows n = sec*1024 + h*64 + d, cols C (bf16)
__global__ __launch_bounds__(256) void transpose_qkv_kernel(
    const float* __restrict__ Wq, const float* __restrict__ Wk,
    const float* __restrict__ Wv, __bf16* __restrict__ dst_base) {
  __shared__ float tile[64][65];
  int z = blockIdx.z;                                  // 0..47
  const float* s = (z < 16 ? Wq : (z < 32 ? Wk : Wv)) + (size_t)(z & 15) * 65536;
  __bf16* d = dst_base + (size_t)z * 65536;            // 64 rows x 1024
  int r0 = blockIdx.x * 64;                            // C-tile
  int tx = threadIdx.x & 63, ty = threadIdx.x >> 6;
#pragma unroll
  for (int rr = ty; rr < 64; rr += 4)
    tile[rr][tx] = s[(size_t)(r0 + rr) * 64 + tx];
  __syncthreads();
#pragma unroll
  for (int rr = ty; rr < 64; rr += 4)
    d[(size_t)rr * 1024 + (r0 + tx)] = (__bf16)tile[tx][rr];
}

// ------------------------------------------- transpose f32 [rows x cols] -> bf16 [cols x rows]
__global__ __launch_bounds__(256) void transpose_cast_kernel(
    const float* __restrict__ src, __bf16* __restrict__ dst,
    int src_ld, int dst_ld) {
  __shared__ float tile[64][65];
  int r0 = blockIdx.x * 64, c0 = blockIdx.y * 64;
  int tx = threadIdx.x & 63, ty = threadIdx.x >> 6;
#pragma unroll
  for (int rr = ty; rr < 64; rr += 4)
    tile[rr][tx] = src[(size_t)(r0 + rr) * src_ld + (c0 + tx)];
  __syncthreads();
#pragma unroll
  for (int rr = ty; rr < 64; rr += 4)
    dst[(size_t)(c0 + rr) * dst_ld + (r0 + tx)] = (__bf16)tile[tx][rr];
}

// ---------------------------------------------------------------- GEMM (A row-major, BT = B^T row-major)
// 128x128 tile, BK=32, 256 threads (4 waves 2x2, each 64x64).  Round-3 proven
// 2-phase dbuf structure.  XOR-swizzled LDS -> 0 bank conflicts (r3).
// MODE 0: q (pre-scaled 1/8), k scatter [B,H,T,D]; V-blocks (sec==2) restage
//         the tile through LDS for fully-coalesced 16B vT writes (r6 win).
// MODE 1: fp32 out + bias
template <int MODE>
__global__ __launch_bounds__(256) void gemm_bt_kernel(
    const __bf16* __restrict__ A, const __bf16* __restrict__ BT, int N,
    __bf16* __restrict__ qo, __bf16* __restrict__ ko, __bf16* __restrict__ vo,
    float* __restrict__ Cout, const float* __restrict__ bias) {
  constexpr int K = 1024;
  extern __shared__ __align__(16) char smem_raw[];
  __bf16* Ash = (__bf16*)smem_raw;                 // [2][128*32]
  __bf16* Bsh = Ash + 2 * 128 * 32;                // [2][128*32]
  const int tid = threadIdx.x;
  const int wid = tid >> 6, lane = tid & 63;
  const int fr = lane & 15, fq = lane >> 4;
  const int m0 = blockIdx.x * 128, n0 = blockIdx.y * 128;
  const int wr = wid >> 1, wc = wid & 1;
  const int srow = lane >> 2;
  const int scol = (((lane & 3) ^ ((lane >> 3) & 3))) * 8;   // pre-swizzled src chunk
  const int swz = ((fq ^ ((fr >> 1) & 3))) << 3;             // read-side swizzle

  f32x4 acc[4][4] = {};

  auto stage = [&](int k0, int buf) {
#pragma unroll
    for (int i = 0; i < 2; ++i) {
      int chunk = wid * 2 + i;
      int row = chunk * 16 + srow;
      const __bf16* gA = A + (size_t)(m0 + row) * K + k0 + scol;
      const __bf16* gB = BT + (size_t)(n0 + row) * K + k0 + scol;
      __builtin_amdgcn_global_load_lds((const GAS void*)gA, (LAS void*)&Ash[buf * 4096 + chunk * 512], 16, 0, 0);
      __builtin_amdgcn_global_load_lds((const GAS void*)gB, (LAS void*)&Bsh[buf * 4096 + chunk * 512], 16, 0, 0);
    }
  };

  stage(0, 0);
  __syncthreads();
  int buf = 0;
  for (int k0 = 0; k0 < K; k0 += 32) {
    if (k0 + 32 < K) stage(k0 + 32, buf ^ 1);
    bf16x8 af[4], bfr[4];
#pragma unroll
    for (int mi = 0; mi < 4; ++mi) {
      int r = wr * 64 + mi * 16 + fr;
      af[mi] = *(const bf16x8*)&Ash[buf * 4096 + r * 32 + swz];
    }
#pragma unroll
    for (int ni = 0; ni < 4; ++ni) {
      int r = wc * 64 + ni * 16 + fr;
      bfr[ni] = *(const bf16x8*)&Bsh[buf * 4096 + r * 32 + swz];
    }
    __builtin_amdgcn_s_setprio(1);
#pragma unroll
    for (int mi = 0; mi < 4; ++mi)
#pragma unroll
      for (int ni = 0; ni < 4; ++ni)
        acc[mi][ni] = __builtin_amdgcn_mfma_f32_16x16x32_bf16(af[mi], bfr[ni], acc[mi][ni], 0, 0, 0);
    __builtin_amdgcn_s_setprio(0);
    __syncthreads();
    buf ^= 1;
  }

  if (MODE == 0 && (n0 >> 10) == 2) {
    // ---- V-block: LDS restage for coalesced transposed writes ----
    __bf16* spill = (__bf16*)smem_raw;   // aliases Ash/Bsh; safe after final sync
#pragma unroll
    for (int mi = 0; mi < 4; ++mi)
#pragma unroll
      for (int ni = 0; ni < 4; ++ni) {
        int nl = wc * 64 + ni * 16 + fr;
        int ml = wr * 64 + mi * 16 + fq * 4;   // r packed (t-consecutive)
        bf16x4 pk;
#pragma unroll
        for (int r = 0; r < 4; ++r) pk[r] = (__bf16)acc[mi][ni][r];
        *(bf16x4*)&spill[nl * 136 + ml] = pk;
      }
    __syncthreads();
    const int b = m0 >> 10, t0 = m0 & 1023;
    const int lrow = lane >> 4, lch = lane & 15;
#pragma unroll
    for (int i = 0; i < 8; ++i) {
      int nl = wid * 32 + i * 4 + lrow;
      bf16x8 v = *(const bf16x8*)&spill[nl * 136 + lch * 8];
      int nn = (n0 & 1023) + nl;               // h*64+dd
      *(bf16x8*)&vo[(((size_t)b * 16 + (nn >> 6)) * 64 + (nn & 63)) * 1024 + t0 + lch * 8] = v;
    }
    return;
  }

#pragma unroll
  for (int mi = 0; mi < 4; ++mi) {
#pragma unroll
    for (int ni = 0; ni < 4; ++ni) {
      int n = n0 + wc * 64 + ni * 16 + fr;
      int mb = m0 + wr * 64 + mi * 16 + fq * 4;
#pragma unroll
      for (int r = 0; r < 4; ++r) {
        int m = mb + r;
        float val = acc[mi][ni][r];
        if (MODE == 0) {
          int nl = n & 1023;
          int h = nl >> 6, dd = nl & 63;
          int b = m >> 10, t = m & 1023;
          if ((n >> 10) == 0) {
            qo[(((size_t)b * 16 + h) * 1024 + t) * 64 + dd] = (__bf16)(val * 0.125f);
          } else {
            ko[(((size_t)b * 16 + h) * 1024 + t) * 64 + dd] = (__bf16)val;
          }
        } else {
          Cout[(size_t)m * N + n] = val + bias[n];
        }
      }
    }
  }
}

// ---------------------------------------------------------------- flash attention (causal)
// 1024 blocks, 256 threads = 4 waves.  One q-tile per block (qt = 15 - bid>>6:
// LPT order, longest blocks dispatch first).  bh = bid & 63 -> all 16 blocks
// of one bh share bid%8 -> same XCD -> K/V (256KB/bh) L2-resident.
// Defer-max (T13, THR=8): skip alpha/rescale when tile max grows <= 8.
__global__ __launch_bounds__(256) void attn_fwd_kernel(
    const __bf16* __restrict__ Q, const __bf16* __restrict__ Kg,
    const __bf16* __restrict__ Vt, __bf16* __restrict__ O) {
  __shared__ __align__(16) __bf16 Ksh[2][64 * 64];
  __shared__ __align__(16) __bf16 VTs[2][64 * 64];
  __shared__ __align__(16) __bf16 Psh[4][16 * 72];

  const int bid = blockIdx.x;
  const int qt = 15 - (bid >> 6);
  const int bh = bid & 63;
  const int b = bh >> 4, h = bh & 15;
  const size_t base = (size_t)bh * 1024 * 64;
  const int tid = threadIdx.x, wid = tid >> 6, lane = tid & 63;
  const int fr = lane & 15, fq = lane >> 4;
  const int q0 = qt * 64;

  bf16x8 qf[2];
  {
    int qr = q0 + wid * 16 + fr;
    qf[0] = *(const bf16x8*)&Q[base + (size_t)qr * 64 + fq * 8];
    qf[1] = *(const bf16x8*)&Q[base + (size_t)qr * 64 + 32 + fq * 8];
  }
  f32x4 oacc[4] = {};
  float m = -1e30f, l = 0.f;   // state for row q = q0 + wid*16 + fr

  const int lrow8 = lane >> 3;
  const int schunk = (lane & 7) ^ lrow8;

  auto stage = [&](int st, int buf) {
    const int s0 = st * 64;
#pragma unroll
    for (int i = 0; i < 2; ++i) {
      int rowbase = i * 32 + wid * 8;
      int row = rowbase + lrow8;
      const __bf16* gK = Kg + base + (size_t)(s0 + row) * 64 + schunk * 8;
      __builtin_amdgcn_global_load_lds((const GAS void*)gK,
          (LAS void*)&Ksh[buf][rowbase * 64], 16, 0, 0);
      const __bf16* gV = Vt + base + (size_t)row * 1024 + s0 + schunk * 8;
      __builtin_amdgcn_global_load_lds((const GAS void*)gV,
          (LAS void*)&VTs[buf][rowbase * 64], 16, 0, 0);
    }
  };

  auto compute = [&](int buf, int s0, bool maskT) {
    // S^T = K Q^T : lane holds s = sf*16+fq*4+r, q = fr
    f32x4 s[4];
    __builtin_amdgcn_s_setprio(1);
#pragma unroll
    for (int sf = 0; sf < 4; ++sf) {
      int row = sf * 16 + fr, rx = fr & 7;
      bf16x8 kf0 = *(const bf16x8*)&Ksh[buf][row * 64 + ((fq ^ rx) << 3)];
      f32x4 z = {};
      s[sf] = __builtin_amdgcn_mfma_f32_16x16x32_bf16(kf0, qf[0], z, 0, 0, 0);
      bf16x8 kf1 = *(const bf16x8*)&Ksh[buf][row * 64 + (((4 + fq) ^ rx) << 3)];
      s[sf] = __builtin_amdgcn_mfma_f32_16x16x32_bf16(kf1, qf[1], s[sf], 0, 0, 0);
    }
    __builtin_amdgcn_s_setprio(0);

    const int qg = q0 + wid * 16 + fr;
    float sv[4][4];
    float mx = -1e30f;
#pragma unroll
    for (int sf = 0; sf < 4; ++sf)
#pragma unroll
      for (int r = 0; r < 4; ++r) {
        float x = s[sf][r];
        if (maskT) { int sg = s0 + sf * 16 + fq * 4 + r; if (sg > qg) x = -1e30f; }
        sv[sf][r] = x;
        mx = fmaxf(mx, x);
      }
    mx = fmaxf(mx, __shfl_xor(mx, 16));
    mx = fmaxf(mx, __shfl_xor(mx, 32));
    // defer-max: rescale only when tile max grew past THR=8 (rare)
    if (__any(mx - m > 8.0f)) {
      float mnew = fmaxf(m, mx);
      float alpha = __expf(m - mnew);
      m = mnew;
      l *= alpha;
      float ar[4];
#pragma unroll
      for (int r = 0; r < 4; ++r) ar[r] = __shfl(alpha, (lane & 48) | (fq * 4 + r));
#pragma unroll
      for (int df = 0; df < 4; ++df)
#pragma unroll
        for (int r = 0; r < 4; ++r) oacc[df][r] *= ar[r];
    }
    float rs = 0.f;
#pragma unroll
    for (int sf = 0; sf < 4; ++sf) {
      bf16x4 pk;
#pragma unroll
      for (int r = 0; r < 4; ++r) {
        float p = __expf(sv[sf][r] - m);
        rs += p;
        pk[r] = (__bf16)p;
      }
      *(bf16x4*)&Psh[wid][fr * 72 + sf * 16 + fq * 4] = pk;  // P[q=fr][s]
    }
    rs += __shfl_xor(rs, 16);
    rs += __shfl_xor(rs, 32);
    l += rs;

    // O += P V : A = P rows (q_local=fr), B = VT rows (d)
    __builtin_amdgcn_s_setprio(1);
#pragma unroll
    for (int kk = 0; kk < 2; ++kk) {
      bf16x8 pf = *(const bf16x8*)&Psh[wid][fr * 72 + kk * 32 + fq * 8];
#pragma unroll
      for (int df = 0; df < 4; ++df) {
        int row = df * 16 + fr;
        bf16x8 vf = *(const bf16x8*)&VTs[buf][row * 64 + ((((kk << 2) | fq) ^ (fr & 7)) << 3)];
        oacc[df] = __builtin_amdgcn_mfma_f32_16x16x32_bf16(pf, vf, oacc[df], 0, 0, 0);
      }
    }
    __builtin_amdgcn_s_setprio(0);
  };

  stage(0, 0);
  __syncthreads();
  int cur = 0;
  for (int st = 0; st <= qt; ++st) {
    if (st < qt) stage(st + 1, cur ^ 1);
    compute(cur, st * 64, st == qt);
    __syncthreads();
    cur ^= 1;
  }

  // epilogue
  float lr[4];
#pragma unroll
  for (int r = 0; r < 4; ++r) lr[r] = __shfl(l, (lane & 48) | (fq * 4 + r));
#pragma unroll
  for (int r = 0; r < 4; ++r) {
    float inv = 1.0f / lr[r];
    int t = q0 + wid * 16 + fq * 4 + r;
    size_t orow = ((size_t)b * 1024 + t) * 1024 + h * 64;
#pragma unroll
    for (int df = 0; df < 4; ++df)
      O[orow + df * 16 + fr] = (__bf16)(oacc[df][r] * inv);
  }
}

// ---------------------------------------------------------------- launch
extern "C" void kernel_launch(void* const* d_in, const int* in_sizes, int n_in,
                              void* d_out, int out_size, void* d_ws, size_t ws_size,
                              hipStream_t stream) {
  const float* x  = (const float*)d_in[0];
  const float* Wq = (const float*)d_in[1];
  const float* Wk = (const float*)d_in[2];
  const float* Wv = (const float*)d_in[3];
  const float* Wo = (const float*)d_in[4];
  const float* bo = (const float*)d_in[5];
  float* out = (float*)d_out;

  __bf16* xb    = (__bf16*)d_ws;                    // 4096x1024
  __bf16* wqkvT = xb + (size_t)4096 * 1024;         // 3072x1024
  __bf16* woT   = wqkvT + (size_t)3072 * 1024;      // 1024x1024
  __bf16* qb    = woT + (size_t)1024 * 1024;        // [B,H,T,D]
  __bf16* kb    = qb + (size_t)4 * 16 * 1024 * 64;  // [B,H,T,D]
  __bf16* vtb   = kb + (size_t)4 * 16 * 1024 * 64;  // [B,H,D,T]
  __bf16* Ob    = vtb + (size_t)4 * 16 * 1024 * 64; // [B*T, H*D]

  cast_bf16_kernel<<<4096, 256, 0, stream>>>(x, xb, 4194304 / 4);
  transpose_qkv_kernel<<<dim3(16, 1, 48), 256, 0, stream>>>(Wq, Wk, Wv, wqkvT);
  transpose_cast_kernel<<<dim3(16, 16), 256, 0, stream>>>(Wo, woT, 1024, 1024);

  // QKV projection: [4096,1024] @ [1024,3072]   (dyn LDS: 32KB dbuf, 34KB V-restage)
  gemm_bt_kernel<0><<<dim3(32, 24), 256, 34816, stream>>>(xb, wqkvT, 3072, qb, kb, vtb, nullptr, nullptr);

  // causal flash attention (one q-tile per block, LPT order, XCD-grouped by bh)
  attn_fwd_kernel<<<1024, 256, 0, stream>>>(qb, kb, vtb, Ob);

  // output projection + bias: [4096,1024] @ [1024,1024]
  gemm_bt_kernel<1><<<dim3(32, 8), 256, 32768, stream>>>(Ob, woT, 1024,
      nullptr, nullptr, nullptr, out, bo);
}